// Round 17
// baseline (244.111 us; speedup 1.0000x reference)
//
#include <hip/hip_runtime.h>
#include <hip/hip_fp16.h>
#include <math.h>

#define NN 100000
#define NE 1200000
#define INC 128
#define HIDC 64
#define EPSV 1e-5f
#define NPB 1024                               // nodes per bucket
#define NBUCK ((NN + NPB - 1) / NPB)           // 98
#define PCAP 16384                             // pairs capacity per bucket (max ~12.9K)
#define SCAP 24576                             // padded srcSorted capacity per bucket
#define CHUNK 8192                             // edges per partA block

typedef float f4 __attribute__((ext_vector_type(4)));
typedef _Float16 hf;
typedef _Float16 h8 __attribute__((ext_vector_type(8)));
typedef unsigned int u32;
typedef unsigned long long u64;

// ---- init: bucket cursors, stats zero, weight prep, dummy hp row zero ----
__global__ __launch_bounds__(256) void k_binit(
    int* bucketCur, float* stats,
    const float* __restrict__ W1, const float* __restrict__ W2,
    hf* __restrict__ w1t, hf* __restrict__ w2t, hf* __restrict__ hp) {
    int t = threadIdx.x;
    if (t < NBUCK) bucketCur[t] = t * PCAP;
    if (t < 256) stats[t] = 0.f;
    if (t < HIDC) hp[(size_t)NN * HIDC + t] = (hf)0.f;   // dummy row for padded edges
    for (int i = t; i < 64 * 128; i += 256) {
        int c = i >> 7, k = i & 127;
        w1t[i] = (hf)W1[k * 64 + c];
    }
    for (int i = t; i < 64 * 64; i += 256) {
        int c = i >> 6, k = i & 63;
        w2t[i] = (hf)W2[k * 64 + c];
    }
}

// ---- pass A: single-hist-pass partition; rank saved packed (d | rank<<17) ----
__global__ __launch_bounds__(256) void k_partA(
    const int* __restrict__ src, const int* __restrict__ dst,
    int* bucketCur, u32* __restrict__ pairs) {
    __shared__ int hist[NBUCK], base[NBUCK];
    int t = threadIdx.x;
    if (t < NBUCK) hist[t] = 0;
    __syncthreads();
    int e0 = blockIdx.x * CHUNK;
    u32 pk[32];
#pragma unroll
    for (int j = 0; j < 32; ++j) {
        int e = e0 + j * 256 + t;
        int d = (e < NE) ? dst[e] : -1;
        if (d >= 0) {
            int r = atomicAdd(&hist[d >> 10], 1);   // r < 8192, fits 15 bits
            pk[j] = (u32)d | ((u32)r << 17);
        } else {
            pk[j] = 0xFFFFFFFFu;                    // unreachable by valid (d,r)
        }
    }
    __syncthreads();
    if (t < NBUCK) base[t] = hist[t] ? atomicAdd(&bucketCur[t], hist[t]) : 0;
    __syncthreads();
#pragma unroll
    for (int j = 0; j < 32; ++j) {
        u32 p = pk[j];
        if (p != 0xFFFFFFFFu) {
            int d = (int)(p & 0x1FFFFu);
            int r = (int)(p >> 17);
            int e = e0 + j * 256 + t;
            pairs[base[d >> 10] + r] = ((u32)(d & 1023) << 17) | (u32)src[e];
        }
    }
}

// ---- pass B: per-bucket counts -> 16-padded segments; cursor/dinv; pad fill + scatter ----
__global__ __launch_bounds__(256) void k_partB(
    const int* __restrict__ bucketCur, const u32* __restrict__ pairs,
    int* __restrict__ srcSorted, u64* __restrict__ cursPacked, float* __restrict__ dinv) {
    __shared__ int cnt1024[NPB];
    __shared__ int off1024[NPB];
    __shared__ int part[256];
    int b = blockIdx.x, t = threadIdx.x;
    int nbase = b * NPB;
    int pbeg = b * PCAP;
    int pend = bucketCur[b];             // pbeg + real count
    int sbeg = b * SCAP;
    for (int i = t; i < NPB; i += 256) cnt1024[i] = 0;
    __syncthreads();
    for (int i = pbeg + t; i < pend; i += 256)
        atomicAdd(&cnt1024[pairs[i] >> 17], 1);
    __syncthreads();
    int c[4], pc[4]; int s = 0;
#pragma unroll
    for (int j = 0; j < 4; ++j) {
        c[j] = cnt1024[t * 4 + j];
        pc[j] = (c[j] + 15) & ~15;       // pad to multiple of 16
        s += pc[j];
    }
    part[t] = s;
    __syncthreads();
    for (int off = 1; off < 256; off <<= 1) {
        int x = (t >= off) ? part[t - off] : 0;
        __syncthreads();
        part[t] += x;
        __syncthreads();
    }
    int run = part[t] - s;               // exclusive prefix of padded counts
#pragma unroll
    for (int j = 0; j < 4; ++j) {
        int node = nbase + t * 4 + j;
        if (node < NN) {
            int nb = sbeg + run;
            cursPacked[node] = ((u64)(u32)(nb + pc[j]) << 32) | (u32)nb;
            off1024[t * 4 + j] = run;
            dinv[node] = rsqrtf((float)c[j] + 1.0f);
            for (int p = c[j]; p < pc[j]; ++p) srcSorted[nb + p] = NN;   // pad slots only
            run += pc[j];
        }
    }
    __syncthreads();
    for (int i = pbeg + t; i < pend; i += 256) {
        u32 p = pairs[i];
        int dl = (int)(p >> 17);
        int pos = sbeg + atomicAdd(&off1024[dl], 1);
        srcSorted[pos] = (int)(p & 0x1FFFFu);
    }
}

// ---------------- layer-1 GEMM via MFMA ----------------
__global__ __launch_bounds__(256) void k_gemm1(
    const float* __restrict__ x, const hf* __restrict__ w1t,
    const float* __restrict__ dinv, hf* __restrict__ hp) {
    int wv = threadIdx.x >> 6, l = threadIdx.x & 63;
    int r16 = l & 15, kg = l >> 4;
    int nodeBase = blockIdx.x * 64;
    int row = nodeBase + wv * 16 + r16;
    int rowC = row < NN ? row : NN - 1;
    const float* xr = x + (size_t)rowC * INC + kg * 8;
    f4 acc[4] = {{0.f,0.f,0.f,0.f},{0.f,0.f,0.f,0.f},{0.f,0.f,0.f,0.f},{0.f,0.f,0.f,0.f}};
#pragma unroll
    for (int ks = 0; ks < 4; ++ks) {
        f4 alo = *(const f4*)(xr + ks * 32);
        f4 ahi = *(const f4*)(xr + ks * 32 + 4);
        h8 a;
#pragma unroll
        for (int j = 0; j < 4; ++j) { a[j] = (hf)alo[j]; a[4 + j] = (hf)ahi[j]; }
#pragma unroll
        for (int n = 0; n < 4; ++n) {
            h8 b = *(const h8*)(w1t + (n * 16 + r16) * INC + ks * 32 + kg * 8);
            acc[n] = __builtin_amdgcn_mfma_f32_16x16x32_f16(a, b, acc[n], 0, 0, 0);
        }
    }
#pragma unroll
    for (int j = 0; j < 4; ++j) {
        int nrow = nodeBase + wv * 16 + kg * 4 + j;
        if (nrow < NN) {
            float dv = dinv[nrow];
            size_t o = (size_t)nrow * HIDC + r16;
#pragma unroll
            for (int n = 0; n < 4; ++n)
                hp[o + n * 16] = (hf)(acc[n][j] * dv);
        }
    }
}

// ---------------- layer-2 GEMM via MFMA, BN (from raw stats) + ReLU fused ----------------
__global__ __launch_bounds__(256) void k_gemm2(
    const hf* __restrict__ agg, const hf* __restrict__ w2t,
    const float* __restrict__ gsum, const float* __restrict__ gsq,
    const float* __restrict__ g, const float* __restrict__ be,
    const float* __restrict__ dinv, hf* __restrict__ hp) {
    __shared__ float ssc[HIDC], ssh[HIDC];
    int tid = threadIdx.x;
    if (tid < HIDC) {
        float mu = gsum[tid] * (1.0f / NN);
        float var = gsq[tid] * (1.0f / NN) - mu * mu;
        float inv = rsqrtf(var + EPSV);
        float sc = g[tid] * inv;
        ssc[tid] = sc;
        ssh[tid] = be[tid] - mu * sc;
    }
    __syncthreads();
    int wv = tid >> 6, l = tid & 63;
    int r16 = l & 15, kg = l >> 4;
    int nodeBase = blockIdx.x * 64;
    int row = nodeBase + wv * 16 + r16;
    int rowC = row < NN ? row : NN - 1;
    const hf* ar = agg + (size_t)rowC * HIDC + kg * 8;
    f4 acc[4] = {{0.f,0.f,0.f,0.f},{0.f,0.f,0.f,0.f},{0.f,0.f,0.f,0.f},{0.f,0.f,0.f,0.f}};
#pragma unroll
    for (int ks = 0; ks < 2; ++ks) {
        h8 raw = *(const h8*)(ar + ks * 32);
        int ch0 = ks * 32 + kg * 8;
        h8 a;
#pragma unroll
        for (int j = 0; j < 8; ++j) {
            float v = (float)raw[j] * ssc[ch0 + j] + ssh[ch0 + j];
            a[j] = (hf)fmaxf(v, 0.f);
        }
#pragma unroll
        for (int n = 0; n < 4; ++n) {
            h8 b = *(const h8*)(w2t + (n * 16 + r16) * HIDC + ks * 32 + kg * 8);
            acc[n] = __builtin_amdgcn_mfma_f32_16x16x32_f16(a, b, acc[n], 0, 0, 0);
        }
    }
#pragma unroll
    for (int j = 0; j < 4; ++j) {
        int nrow = nodeBase + wv * 16 + kg * 4 + j;
        if (nrow < NN) {
            float dv = dinv[nrow];
            size_t o = (size_t)nrow * HIDC + r16;
#pragma unroll
            for (int n = 0; n < 4; ++n)
                hp[o + n * 16] = (hf)(acc[n][j] * dv);
        }
    }
}

// ---------------- CSR gather: 4 nodes/wave (4 independent chains), scalar index loads ----------------
// All segment bounds in SGPRs; guards are scalar branches (no shfl anywhere).
// __launch_bounds__(256,2) lifts the VGPR cap so up to 64 row loads stay in flight.
__global__ __launch_bounds__(256, 2) void k_gather(
    const u64* __restrict__ cursPacked, const int* __restrict__ srcSorted,
    const float* __restrict__ dinv, const hf* __restrict__ hp,
    hf* __restrict__ agg) {
    int wid = threadIdx.x >> 6, lane = threadIdx.x & 63;
    int n0 = blockIdx.x * 16 + wid;     // NN = 100000 = 16 * 6250, always valid
    int n1 = n0 + 4, n2 = n0 + 8, n3 = n0 + 12;
    u64 ce0 = cursPacked[n0], ce1 = cursPacked[n1];
    u64 ce2 = cursPacked[n2], ce3 = cursPacked[n3];
    float dv0 = dinv[n0], dv1 = dinv[n1], dv2 = dinv[n2], dv3 = dinv[n3];
    int beg0 = __builtin_amdgcn_readfirstlane((int)(ce0 & 0xffffffffu));
    int end0 = __builtin_amdgcn_readfirstlane((int)(ce0 >> 32));
    int beg1 = __builtin_amdgcn_readfirstlane((int)(ce1 & 0xffffffffu));
    int end1 = __builtin_amdgcn_readfirstlane((int)(ce1 >> 32));
    int beg2 = __builtin_amdgcn_readfirstlane((int)(ce2 & 0xffffffffu));
    int end2 = __builtin_amdgcn_readfirstlane((int)(ce2 >> 32));
    int beg3 = __builtin_amdgcn_readfirstlane((int)(ce3 & 0xffffffffu));
    int end3 = __builtin_amdgcn_readfirstlane((int)(ce3 >> 32));
    float a0A = (float)hp[(size_t)n0 * HIDC + lane], a0B = 0.f;   // self-loops
    float a1A = (float)hp[(size_t)n1 * HIDC + lane], a1B = 0.f;
    float a2A = (float)hp[(size_t)n2 * HIDC + lane], a2B = 0.f;
    float a3A = (float)hp[(size_t)n3 * HIDC + lane], a3B = 0.f;
    int nb0 = (end0 - beg0) >> 4, nb1 = (end1 - beg1) >> 4;
    int nb2 = (end2 - beg2) >> 4, nb3 = (end3 - beg3) >> 4;
    int nbmax = nb0 > nb1 ? nb0 : nb1;
    if (nb2 > nbmax) nbmax = nb2;
    if (nb3 > nbmax) nbmax = nb3;
    for (int i = 0; i < nbmax; ++i) {
        bool d0 = i < nb0, d1 = i < nb1, d2 = i < nb2, d3 = i < nb3;   // scalar guards
        float v0[16], v1[16], v2[16], v3[16];
        if (d0) {
            const int* sp = srcSorted + beg0 + i * 16;
#pragma unroll
            for (int j = 0; j < 16; ++j) v0[j] = (float)hp[(size_t)sp[j] * HIDC + lane];
        }
        if (d1) {
            const int* sp = srcSorted + beg1 + i * 16;
#pragma unroll
            for (int j = 0; j < 16; ++j) v1[j] = (float)hp[(size_t)sp[j] * HIDC + lane];
        }
        if (d2) {
            const int* sp = srcSorted + beg2 + i * 16;
#pragma unroll
            for (int j = 0; j < 16; ++j) v2[j] = (float)hp[(size_t)sp[j] * HIDC + lane];
        }
        if (d3) {
            const int* sp = srcSorted + beg3 + i * 16;
#pragma unroll
            for (int j = 0; j < 16; ++j) v3[j] = (float)hp[(size_t)sp[j] * HIDC + lane];
        }
        if (d0) {
            a0A += (((v0[0] + v0[1]) + (v0[2] + v0[3])) + ((v0[4] + v0[5]) + (v0[6] + v0[7])));
            a0B += (((v0[8] + v0[9]) + (v0[10] + v0[11])) + ((v0[12] + v0[13]) + (v0[14] + v0[15])));
        }
        if (d1) {
            a1A += (((v1[0] + v1[1]) + (v1[2] + v1[3])) + ((v1[4] + v1[5]) + (v1[6] + v1[7])));
            a1B += (((v1[8] + v1[9]) + (v1[10] + v1[11])) + ((v1[12] + v1[13]) + (v1[14] + v1[15])));
        }
        if (d2) {
            a2A += (((v2[0] + v2[1]) + (v2[2] + v2[3])) + ((v2[4] + v2[5]) + (v2[6] + v2[7])));
            a2B += (((v2[8] + v2[9]) + (v2[10] + v2[11])) + ((v2[12] + v2[13]) + (v2[14] + v2[15])));
        }
        if (d3) {
            a3A += (((v3[0] + v3[1]) + (v3[2] + v3[3])) + ((v3[4] + v3[5]) + (v3[6] + v3[7])));
            a3B += (((v3[8] + v3[9]) + (v3[10] + v3[11])) + ((v3[12] + v3[13]) + (v3[14] + v3[15])));
        }
    }
    agg[(size_t)n0 * HIDC + lane] = (hf)(dv0 * (a0A + a0B));
    agg[(size_t)n1 * HIDC + lane] = (hf)(dv1 * (a1A + a1B));
    agg[(size_t)n2 * HIDC + lane] = (hf)(dv2 * (a2A + a2B));
    agg[(size_t)n3 * HIDC + lane] = (hf)(dv3 * (a3A + a3B));
}

// ---------------- BN statistics: h8 vectorized loads, LDS transpose-reduce ----------------
__global__ __launch_bounds__(256) void k_stats(
    const hf* __restrict__ agg, float* gsum, float* gsq) {
    __shared__ float ls[256][8], lq[256][8];
    int tid = threadIdx.x;
    int cg = tid & 7, r = tid >> 3;         // 8 ch-groups x 32 rows per block-iter
    f4 sA = {0.f,0.f,0.f,0.f}, sB = sA, qA = sA, qB = sA;
    for (int n = blockIdx.x * 32 + r; n < NN; n += 512 * 32) {
        h8 v = *(const h8*)&agg[(size_t)n * HIDC + cg * 8];
#pragma unroll
        for (int j = 0; j < 4; ++j) {
            float a = (float)v[j], b = (float)v[4 + j];
            sA[j] += a; qA[j] += a * a;
            sB[j] += b; qB[j] += b * b;
        }
    }
#pragma unroll
    for (int j = 0; j < 4; ++j) {
        ls[tid][j] = sA[j]; ls[tid][4 + j] = sB[j];
        lq[tid][j] = qA[j]; lq[tid][4 + j] = qB[j];
    }
    __syncthreads();
    if (tid < 64) {
        int cgi = tid >> 3, ji = tid & 7;   // channel = cgi*8 + ji
        float s = 0.f, q = 0.f;
        for (int rr = 0; rr < 32; ++rr) {
            s += ls[cgi + rr * 8][ji];
            q += lq[cgi + rr * 8][ji];
        }
        atomicAdd(&gsum[tid], s);
        atomicAdd(&gsq[tid], q);
    }
}

// ---------------- MLP head, BN (from raw stats) + ReLU fused ----------------
__global__ __launch_bounds__(256) void k_mlp(
    const hf* __restrict__ agg,
    const float* __restrict__ gsum, const float* __restrict__ gsq,
    const float* __restrict__ g, const float* __restrict__ be,
    const float* __restrict__ Wm1, const float* __restrict__ bm1,
    const float* __restrict__ Wm2, const float* __restrict__ bm2,
    const float* __restrict__ Wm3, const float* __restrict__ bm3,
    float* __restrict__ out) {
    __shared__ float ssc[HIDC], ssh[HIDC];
    int tid = threadIdx.x;
    if (tid < HIDC) {
        float mu = gsum[tid] * (1.0f / NN);
        float var = gsq[tid] * (1.0f / NN) - mu * mu;
        float inv = rsqrtf(var + EPSV);
        float sc = g[tid] * inv;
        ssc[tid] = sc;
        ssh[tid] = be[tid] - mu * sc;
    }
    __syncthreads();
    int n = blockIdx.x * blockDim.x + tid;
    if (n >= NN) return;
    float h[HIDC];
#pragma unroll
    for (int cq = 0; cq < 8; ++cq) {
        h8 v8 = *(const h8*)&agg[(size_t)n * HIDC + cq * 8];
#pragma unroll
        for (int j = 0; j < 8; ++j) {
            int c = cq * 8 + j;
            h[c] = fmaxf((float)v8[j] * ssc[c] + ssh[c], 0.0f);
        }
    }
    float a1[32];
#pragma unroll
    for (int j = 0; j < 32; ++j) {
        float acc = bm1[j];
#pragma unroll
        for (int c = 0; c < HIDC; ++c) acc += h[c] * Wm1[c * 32 + j];
        a1[j] = fmaxf(acc, 0.0f);
    }
    float a2[16];
#pragma unroll
    for (int j = 0; j < 16; ++j) {
        float acc = bm2[j];
#pragma unroll
        for (int c = 0; c < 32; ++c) acc += a1[c] * Wm2[c * 16 + j];
        a2[j] = fmaxf(acc, 0.0f);
    }
    float z = bm3[0];
#pragma unroll
    for (int c = 0; c < 16; ++c) z += a2[c] * Wm3[c];
    out[n] = 1.0f / (1.0f + expf(-z));
}

extern "C" void kernel_launch(void* const* d_in, const int* in_sizes, int n_in,
                              void* d_out, int out_size, void* d_ws, size_t ws_size,
                              hipStream_t stream) {
    const float* x   = (const float*)d_in[0];
    const int*   ei  = (const int*)d_in[1];
    const float* W1  = (const float*)d_in[2];
    // b1 (d_in[3]) cancels in BatchNorm
    const float* g1  = (const float*)d_in[4];
    const float* be1 = (const float*)d_in[5];
    const float* W2  = (const float*)d_in[6];
    // b2 (d_in[7]) cancels in BatchNorm
    const float* g2  = (const float*)d_in[8];
    const float* be2 = (const float*)d_in[9];
    const float* Wm1 = (const float*)d_in[10];
    const float* bm1 = (const float*)d_in[11];
    const float* Wm2 = (const float*)d_in[12];
    const float* bm2 = (const float*)d_in[13];
    const float* Wm3 = (const float*)d_in[14];
    const float* bm3 = (const float*)d_in[15];
    float* out = (float*)d_out;

    const int* srcI = ei;
    const int* dstI = ei + NE;

    const size_t PCAPT = (size_t)NBUCK * PCAP;          // u32 pairs capacity
    const size_t SCAPT = (size_t)NBUCK * SCAP;          // padded srcSorted capacity
    int*   bucketCur = (int*)d_ws;                      // 128
    float* stats     = (float*)(bucketCur + 128);       // 512
    u64*   cursPacked= (u64*)(stats + 512);             // NN u64 (8B-aligned)
    int*   srcSorted = (int*)(cursPacked + NN);         // SCAPT ints
    float* dinv      = (float*)(srcSorted + SCAPT);     // NN
    hf*    w1t       = (hf*)(dinv + NN);                // 8192
    hf*    w2t       = w1t + 64 * 128;                  // 4096
    hf*    hp        = w2t + 64 * 64;                   // (NN+1)*64 fp16 (+dummy row)
    hf*    agg       = hp + (size_t)(NN + 1) * HIDC;    // NN*64 fp16
    u32*   pairs     = (u32*)(agg + (size_t)NN * HIDC); // PCAPT u32
    float *sum1 = stats,       *sq1 = stats + 64;
    float *sum2 = stats + 128, *sq2 = stats + 192;

    // CSR build: init -> partition (single-hist-pass) -> per-bucket finalize
    k_binit<<<1, 256, 0, stream>>>(bucketCur, stats, W1, W2, w1t, w2t, hp);
    k_partA<<<(NE + CHUNK - 1) / CHUNK, 256, 0, stream>>>(srcI, dstI, bucketCur, pairs);
    k_partB<<<NBUCK, 256, 0, stream>>>(bucketCur, pairs, srcSorted, cursPacked, dinv);

    // layer 1
    k_gemm1<<<(NN + 63) / 64, 256, 0, stream>>>(x, w1t, dinv, hp);
    k_gather<<<NN / 16, 256, 0, stream>>>(cursPacked, srcSorted, dinv, hp, agg);
    k_stats<<<512, 256, 0, stream>>>(agg, sum1, sq1);

    // layer 2 (BN folded into gemm2 from raw sums)
    k_gemm2<<<(NN + 63) / 64, 256, 0, stream>>>(agg, w2t, sum1, sq1, g1, be1, dinv, hp);
    k_gather<<<NN / 16, 256, 0, stream>>>(cursPacked, srcSorted, dinv, hp, agg);
    k_stats<<<512, 256, 0, stream>>>(agg, sum2, sq2);

    // MLP head (BN folded in from raw sums)
    k_mlp<<<(NN + 255) / 256, 256, 0, stream>>>(agg, sum2, sq2, g2, be2,
                                                Wm1, bm1, Wm2, bm2, Wm3, bm3, out);
}

// Round 18
// 214.750 us; speedup vs baseline: 1.1367x; 1.1367x over previous
//
#include <hip/hip_runtime.h>
#include <hip/hip_fp16.h>
#include <math.h>

#define NN 100000
#define NE 1200000
#define INC 128
#define HIDC 64
#define EPSV 1e-5f
#define NPB 1024                               // nodes per bucket
#define NBUCK ((NN + NPB - 1) / NPB)           // 98
#define PCAP 16384                             // pairs capacity per bucket (max ~12.9K)
#define SCAP 24576                             // padded srcSorted capacity per bucket
#define CHUNK 4096                             // edges per partA block

typedef float f4 __attribute__((ext_vector_type(4)));
typedef _Float16 hf;
typedef _Float16 h8 __attribute__((ext_vector_type(8)));
typedef unsigned int u32;
typedef unsigned long long u64;

// ---- init: bucket cursors, stats zero, weight prep, dummy hp row zero ----
__global__ __launch_bounds__(256) void k_binit(
    int* bucketCur, float* stats,
    const float* __restrict__ W1, const float* __restrict__ W2,
    hf* __restrict__ w1t, hf* __restrict__ w2t, hf* __restrict__ hp) {
    int t = threadIdx.x;
    if (t < NBUCK) bucketCur[t] = t * PCAP;
    if (t < 256) stats[t] = 0.f;
    if (t < HIDC) hp[(size_t)NN * HIDC + t] = (hf)0.f;   // dummy row for padded edges
    for (int i = t; i < 64 * 128; i += 256) {
        int c = i >> 7, k = i & 127;
        w1t[i] = (hf)W1[k * 64 + c];
    }
    for (int i = t; i < 64 * 64; i += 256) {
        int c = i >> 6, k = i & 63;
        w2t[i] = (hf)W2[k * 64 + c];
    }
}

// ---- pass A: single-hist-pass partition; rank saved packed (d | rank<<17) ----
__global__ __launch_bounds__(256) void k_partA(
    const int* __restrict__ src, const int* __restrict__ dst,
    int* bucketCur, u32* __restrict__ pairs) {
    __shared__ int hist[NBUCK], base[NBUCK];
    int t = threadIdx.x;
    if (t < NBUCK) hist[t] = 0;
    __syncthreads();
    int e0 = blockIdx.x * CHUNK;
    u32 pk[16];
#pragma unroll
    for (int j = 0; j < 16; ++j) {
        int e = e0 + j * 256 + t;
        int d = (e < NE) ? dst[e] : -1;
        if (d >= 0) {
            int r = atomicAdd(&hist[d >> 10], 1);   // r < 4096, fits 15 bits
            pk[j] = (u32)d | ((u32)r << 17);
        } else {
            pk[j] = 0xFFFFFFFFu;                    // unreachable by valid (d,r)
        }
    }
    __syncthreads();
    if (t < NBUCK) base[t] = hist[t] ? atomicAdd(&bucketCur[t], hist[t]) : 0;
    __syncthreads();
#pragma unroll
    for (int j = 0; j < 16; ++j) {
        u32 p = pk[j];
        if (p != 0xFFFFFFFFu) {
            int d = (int)(p & 0x1FFFFu);
            int r = (int)(p >> 17);
            int e = e0 + j * 256 + t;
            pairs[base[d >> 10] + r] = ((u32)(d & 1023) << 17) | (u32)src[e];
        }
    }
}

// ---- pass B: per-bucket counts -> 16-padded segments; cursor/dinv; pad fill + scatter ----
__global__ __launch_bounds__(256) void k_partB(
    const int* __restrict__ bucketCur, const u32* __restrict__ pairs,
    int* __restrict__ srcSorted, u64* __restrict__ cursPacked, float* __restrict__ dinv) {
    __shared__ int cnt1024[NPB];
    __shared__ int off1024[NPB];
    __shared__ int part[256];
    int b = blockIdx.x, t = threadIdx.x;
    int nbase = b * NPB;
    int pbeg = b * PCAP;
    int pend = bucketCur[b];             // pbeg + real count
    int sbeg = b * SCAP;
    for (int i = t; i < NPB; i += 256) cnt1024[i] = 0;
    __syncthreads();
    for (int i = pbeg + t; i < pend; i += 256)
        atomicAdd(&cnt1024[pairs[i] >> 17], 1);
    __syncthreads();
    int c[4], pc[4]; int s = 0;
#pragma unroll
    for (int j = 0; j < 4; ++j) {
        c[j] = cnt1024[t * 4 + j];
        pc[j] = (c[j] + 15) & ~15;       // pad to multiple of 16
        s += pc[j];
    }
    part[t] = s;
    __syncthreads();
    for (int off = 1; off < 256; off <<= 1) {
        int x = (t >= off) ? part[t - off] : 0;
        __syncthreads();
        part[t] += x;
        __syncthreads();
    }
    int run = part[t] - s;               // exclusive prefix of padded counts
#pragma unroll
    for (int j = 0; j < 4; ++j) {
        int node = nbase + t * 4 + j;
        if (node < NN) {
            int nb = sbeg + run;
            cursPacked[node] = ((u64)(u32)(nb + pc[j]) << 32) | (u32)nb;
            off1024[t * 4 + j] = run;
            dinv[node] = rsqrtf((float)c[j] + 1.0f);
            for (int p = c[j]; p < pc[j]; ++p) srcSorted[nb + p] = NN;   // pad slots only
            run += pc[j];
        }
    }
    __syncthreads();
    for (int i = pbeg + t; i < pend; i += 256) {
        u32 p = pairs[i];
        int dl = (int)(p >> 17);
        int pos = sbeg + atomicAdd(&off1024[dl], 1);
        srcSorted[pos] = (int)(p & 0x1FFFFu);
    }
}

// ---------------- layer-1 GEMM via MFMA ----------------
__global__ __launch_bounds__(256) void k_gemm1(
    const float* __restrict__ x, const hf* __restrict__ w1t,
    const float* __restrict__ dinv, hf* __restrict__ hp) {
    int wv = threadIdx.x >> 6, l = threadIdx.x & 63;
    int r16 = l & 15, kg = l >> 4;
    int nodeBase = blockIdx.x * 64;
    int row = nodeBase + wv * 16 + r16;
    int rowC = row < NN ? row : NN - 1;
    const float* xr = x + (size_t)rowC * INC + kg * 8;
    f4 acc[4] = {{0.f,0.f,0.f,0.f},{0.f,0.f,0.f,0.f},{0.f,0.f,0.f,0.f},{0.f,0.f,0.f,0.f}};
#pragma unroll
    for (int ks = 0; ks < 4; ++ks) {
        f4 alo = *(const f4*)(xr + ks * 32);
        f4 ahi = *(const f4*)(xr + ks * 32 + 4);
        h8 a;
#pragma unroll
        for (int j = 0; j < 4; ++j) { a[j] = (hf)alo[j]; a[4 + j] = (hf)ahi[j]; }
#pragma unroll
        for (int n = 0; n < 4; ++n) {
            h8 b = *(const h8*)(w1t + (n * 16 + r16) * INC + ks * 32 + kg * 8);
            acc[n] = __builtin_amdgcn_mfma_f32_16x16x32_f16(a, b, acc[n], 0, 0, 0);
        }
    }
#pragma unroll
    for (int j = 0; j < 4; ++j) {
        int nrow = nodeBase + wv * 16 + kg * 4 + j;
        if (nrow < NN) {
            float dv = dinv[nrow];
            size_t o = (size_t)nrow * HIDC + r16;
#pragma unroll
            for (int n = 0; n < 4; ++n)
                hp[o + n * 16] = (hf)(acc[n][j] * dv);
        }
    }
}

// ---------------- layer-2 GEMM via MFMA, BN (from raw stats) + ReLU fused ----------------
__global__ __launch_bounds__(256) void k_gemm2(
    const hf* __restrict__ agg, const hf* __restrict__ w2t,
    const float* __restrict__ gsum, const float* __restrict__ gsq,
    const float* __restrict__ g, const float* __restrict__ be,
    const float* __restrict__ dinv, hf* __restrict__ hp) {
    __shared__ float ssc[HIDC], ssh[HIDC];
    int tid = threadIdx.x;
    if (tid < HIDC) {
        float mu = gsum[tid] * (1.0f / NN);
        float var = gsq[tid] * (1.0f / NN) - mu * mu;
        float inv = rsqrtf(var + EPSV);
        float sc = g[tid] * inv;
        ssc[tid] = sc;
        ssh[tid] = be[tid] - mu * sc;
    }
    __syncthreads();
    int wv = tid >> 6, l = tid & 63;
    int r16 = l & 15, kg = l >> 4;
    int nodeBase = blockIdx.x * 64;
    int row = nodeBase + wv * 16 + r16;
    int rowC = row < NN ? row : NN - 1;
    const hf* ar = agg + (size_t)rowC * HIDC + kg * 8;
    f4 acc[4] = {{0.f,0.f,0.f,0.f},{0.f,0.f,0.f,0.f},{0.f,0.f,0.f,0.f},{0.f,0.f,0.f,0.f}};
#pragma unroll
    for (int ks = 0; ks < 2; ++ks) {
        h8 raw = *(const h8*)(ar + ks * 32);
        int ch0 = ks * 32 + kg * 8;
        h8 a;
#pragma unroll
        for (int j = 0; j < 8; ++j) {
            float v = (float)raw[j] * ssc[ch0 + j] + ssh[ch0 + j];
            a[j] = (hf)fmaxf(v, 0.f);
        }
#pragma unroll
        for (int n = 0; n < 4; ++n) {
            h8 b = *(const h8*)(w2t + (n * 16 + r16) * HIDC + ks * 32 + kg * 8);
            acc[n] = __builtin_amdgcn_mfma_f32_16x16x32_f16(a, b, acc[n], 0, 0, 0);
        }
    }
#pragma unroll
    for (int j = 0; j < 4; ++j) {
        int nrow = nodeBase + wv * 16 + kg * 4 + j;
        if (nrow < NN) {
            float dv = dinv[nrow];
            size_t o = (size_t)nrow * HIDC + r16;
#pragma unroll
            for (int n = 0; n < 4; ++n)
                hp[o + n * 16] = (hf)(acc[n][j] * dv);
        }
    }
}

// ---------------- CSR gather: 2 nodes/wave, SCALAR index loads (R16-proven) ----------------
__global__ __launch_bounds__(256) void k_gather(
    const u64* __restrict__ cursPacked, const int* __restrict__ srcSorted,
    const float* __restrict__ dinv, const hf* __restrict__ hp,
    hf* __restrict__ agg) {
    int wid = threadIdx.x >> 6, lane = threadIdx.x & 63;
    int n0 = blockIdx.x * 8 + wid;      // NN = 100000 = 8 * 12500, always valid
    int n1 = n0 + 4;
    u64 ce0 = cursPacked[n0];
    u64 ce1 = cursPacked[n1];
    float dv0 = dinv[n0], dv1 = dinv[n1];
    int beg0 = __builtin_amdgcn_readfirstlane((int)(ce0 & 0xffffffffu));
    int end0 = __builtin_amdgcn_readfirstlane((int)(ce0 >> 32));
    int beg1 = __builtin_amdgcn_readfirstlane((int)(ce1 & 0xffffffffu));
    int end1 = __builtin_amdgcn_readfirstlane((int)(ce1 >> 32));
    float a0A = (float)hp[(size_t)n0 * HIDC + lane], a0B = 0.f;   // self-loops
    float a1A = (float)hp[(size_t)n1 * HIDC + lane], a1B = 0.f;
    int nb0 = (end0 - beg0) >> 4;
    int nb1 = (end1 - beg1) >> 4;
    int nbmax = nb0 > nb1 ? nb0 : nb1;
    for (int i = 0; i < nbmax; ++i) {
        bool d0 = i < nb0, d1 = i < nb1;   // scalar (SGPR-derived) guards
        float v0[16], v1[16];
        if (d0) {
            const int* sp = srcSorted + beg0 + i * 16;   // fully uniform address
#pragma unroll
            for (int j = 0; j < 16; ++j) {
                int s = sp[j];                           // scalar load
                v0[j] = (float)hp[(size_t)s * HIDC + lane];
            }
        }
        if (d1) {
            const int* sp = srcSorted + beg1 + i * 16;
#pragma unroll
            for (int j = 0; j < 16; ++j) {
                int s = sp[j];
                v1[j] = (float)hp[(size_t)s * HIDC + lane];
            }
        }
        if (d0) {
            a0A += (((v0[0] + v0[1]) + (v0[2] + v0[3])) + ((v0[4] + v0[5]) + (v0[6] + v0[7])));
            a0B += (((v0[8] + v0[9]) + (v0[10] + v0[11])) + ((v0[12] + v0[13]) + (v0[14] + v0[15])));
        }
        if (d1) {
            a1A += (((v1[0] + v1[1]) + (v1[2] + v1[3])) + ((v1[4] + v1[5]) + (v1[6] + v1[7])));
            a1B += (((v1[8] + v1[9]) + (v1[10] + v1[11])) + ((v1[12] + v1[13]) + (v1[14] + v1[15])));
        }
    }
    agg[(size_t)n0 * HIDC + lane] = (hf)(dv0 * (a0A + a0B));
    agg[(size_t)n1 * HIDC + lane] = (hf)(dv1 * (a1A + a1B));
}

// ---------------- BN statistics: h8 vectorized loads, LDS transpose-reduce ----------------
__global__ __launch_bounds__(256) void k_stats(
    const hf* __restrict__ agg, float* gsum, float* gsq) {
    __shared__ float ls[256][8], lq[256][8];
    int tid = threadIdx.x;
    int cg = tid & 7, r = tid >> 3;         // 8 ch-groups x 32 rows per block-iter
    f4 sA = {0.f,0.f,0.f,0.f}, sB = sA, qA = sA, qB = sA;
    for (int n = blockIdx.x * 32 + r; n < NN; n += 512 * 32) {
        h8 v = *(const h8*)&agg[(size_t)n * HIDC + cg * 8];
#pragma unroll
        for (int j = 0; j < 4; ++j) {
            float a = (float)v[j], b = (float)v[4 + j];
            sA[j] += a; qA[j] += a * a;
            sB[j] += b; qB[j] += b * b;
        }
    }
#pragma unroll
    for (int j = 0; j < 4; ++j) {
        ls[tid][j] = sA[j]; ls[tid][4 + j] = sB[j];
        lq[tid][j] = qA[j]; lq[tid][4 + j] = qB[j];
    }
    __syncthreads();
    if (tid < 64) {
        int cgi = tid >> 3, ji = tid & 7;   // channel = cgi*8 + ji
        float s = 0.f, q = 0.f;
        for (int rr = 0; rr < 32; ++rr) {
            s += ls[cgi + rr * 8][ji];
            q += lq[cgi + rr * 8][ji];
        }
        atomicAdd(&gsum[tid], s);
        atomicAdd(&gsq[tid], q);
    }
}

// ---------------- MLP head, BN (from raw stats) + ReLU fused ----------------
__global__ __launch_bounds__(256) void k_mlp(
    const hf* __restrict__ agg,
    const float* __restrict__ gsum, const float* __restrict__ gsq,
    const float* __restrict__ g, const float* __restrict__ be,
    const float* __restrict__ Wm1, const float* __restrict__ bm1,
    const float* __restrict__ Wm2, const float* __restrict__ bm2,
    const float* __restrict__ Wm3, const float* __restrict__ bm3,
    float* __restrict__ out) {
    __shared__ float ssc[HIDC], ssh[HIDC];
    int tid = threadIdx.x;
    if (tid < HIDC) {
        float mu = gsum[tid] * (1.0f / NN);
        float var = gsq[tid] * (1.0f / NN) - mu * mu;
        float inv = rsqrtf(var + EPSV);
        float sc = g[tid] * inv;
        ssc[tid] = sc;
        ssh[tid] = be[tid] - mu * sc;
    }
    __syncthreads();
    int n = blockIdx.x * blockDim.x + tid;
    if (n >= NN) return;
    float h[HIDC];
#pragma unroll
    for (int cq = 0; cq < 8; ++cq) {
        h8 v8 = *(const h8*)&agg[(size_t)n * HIDC + cq * 8];
#pragma unroll
        for (int j = 0; j < 8; ++j) {
            int c = cq * 8 + j;
            h[c] = fmaxf((float)v8[j] * ssc[c] + ssh[c], 0.0f);
        }
    }
    float a1[32];
#pragma unroll
    for (int j = 0; j < 32; ++j) {
        float acc = bm1[j];
#pragma unroll
        for (int c = 0; c < HIDC; ++c) acc += h[c] * Wm1[c * 32 + j];
        a1[j] = fmaxf(acc, 0.0f);
    }
    float a2[16];
#pragma unroll
    for (int j = 0; j < 16; ++j) {
        float acc = bm2[j];
#pragma unroll
        for (int c = 0; c < 32; ++c) acc += a1[c] * Wm2[c * 16 + j];
        a2[j] = fmaxf(acc, 0.0f);
    }
    float z = bm3[0];
#pragma unroll
    for (int c = 0; c < 16; ++c) z += a2[c] * Wm3[c];
    out[n] = 1.0f / (1.0f + expf(-z));
}

extern "C" void kernel_launch(void* const* d_in, const int* in_sizes, int n_in,
                              void* d_out, int out_size, void* d_ws, size_t ws_size,
                              hipStream_t stream) {
    const float* x   = (const float*)d_in[0];
    const int*   ei  = (const int*)d_in[1];
    const float* W1  = (const float*)d_in[2];
    // b1 (d_in[3]) cancels in BatchNorm
    const float* g1  = (const float*)d_in[4];
    const float* be1 = (const float*)d_in[5];
    const float* W2  = (const float*)d_in[6];
    // b2 (d_in[7]) cancels in BatchNorm
    const float* g2  = (const float*)d_in[8];
    const float* be2 = (const float*)d_in[9];
    const float* Wm1 = (const float*)d_in[10];
    const float* bm1 = (const float*)d_in[11];
    const float* Wm2 = (const float*)d_in[12];
    const float* bm2 = (const float*)d_in[13];
    const float* Wm3 = (const float*)d_in[14];
    const float* bm3 = (const float*)d_in[15];
    float* out = (float*)d_out;

    const int* srcI = ei;
    const int* dstI = ei + NE;

    const size_t PCAPT = (size_t)NBUCK * PCAP;          // u32 pairs capacity
    const size_t SCAPT = (size_t)NBUCK * SCAP;          // padded srcSorted capacity
    int*   bucketCur = (int*)d_ws;                      // 128
    float* stats     = (float*)(bucketCur + 128);       // 512
    u64*   cursPacked= (u64*)(stats + 512);             // NN u64 (8B-aligned)
    int*   srcSorted = (int*)(cursPacked + NN);         // SCAPT ints
    float* dinv      = (float*)(srcSorted + SCAPT);     // NN
    hf*    w1t       = (hf*)(dinv + NN);                // 8192
    hf*    w2t       = w1t + 64 * 128;                  // 4096
    hf*    hp        = w2t + 64 * 64;                   // (NN+1)*64 fp16 (+dummy row)
    hf*    agg       = hp + (size_t)(NN + 1) * HIDC;    // NN*64 fp16
    u32*   pairs     = (u32*)(agg + (size_t)NN * HIDC); // PCAPT u32
    float *sum1 = stats,       *sq1 = stats + 64;
    float *sum2 = stats + 128, *sq2 = stats + 192;

    // CSR build: init -> partition (single-hist-pass) -> per-bucket finalize
    k_binit<<<1, 256, 0, stream>>>(bucketCur, stats, W1, W2, w1t, w2t, hp);
    k_partA<<<(NE + CHUNK - 1) / CHUNK, 256, 0, stream>>>(srcI, dstI, bucketCur, pairs);
    k_partB<<<NBUCK, 256, 0, stream>>>(bucketCur, pairs, srcSorted, cursPacked, dinv);

    // layer 1
    k_gemm1<<<(NN + 63) / 64, 256, 0, stream>>>(x, w1t, dinv, hp);
    k_gather<<<NN / 8, 256, 0, stream>>>(cursPacked, srcSorted, dinv, hp, agg);
    k_stats<<<512, 256, 0, stream>>>(agg, sum1, sq1);

    // layer 2 (BN folded into gemm2 from raw sums)
    k_gemm2<<<(NN + 63) / 64, 256, 0, stream>>>(agg, w2t, sum1, sq1, g1, be1, dinv, hp);
    k_gather<<<NN / 8, 256, 0, stream>>>(cursPacked, srcSorted, dinv, hp, agg);
    k_stats<<<512, 256, 0, stream>>>(agg, sum2, sq2);

    // MLP head (BN folded in from raw sums)
    k_mlp<<<(NN + 255) / 256, 256, 0, stream>>>(agg, sum2, sq2, g2, be2,
                                                Wm1, bm1, Wm2, bm2, Wm3, bm3, out);
}